// Round 15
// baseline (363.825 us; speedup 1.0000x reference)
//
#include <hip/hip_runtime.h>

#define LOSS_OFF 8388608
#define IDX_OFF  8388609

// ws layout (bytes)  (total ~1.58 MB)
#define WS_SEE   0          // float[1024]
#define WS_SXX   4096       // float[32768]   -> 135168
#define WS_KEY   135168     // u64[32768]     -> 397312
#define WS_CNT   397312     // int
#define WS_LOSS  397320     // double
#define WS_WL    397328     // int[32768]     -> 528400
#define WS_EP    528448     // packed E frags (1 MB) during k1; REUSED as eT[c][k] (1 MB) after k1

#define FLT_BIG  3.402823466e+38f
#define MARGIN   1.0e-4f

typedef __attribute__((ext_vector_type(8))) short  short8v;
typedef __attribute__((ext_vector_type(4))) float  float4v;

// numpy pairwise_sum of 256 squared elements, bit-exact (round-2 notes).
__device__ __forceinline__ float np_sumsq256(const float* __restrict__ p, int stride) {
    float s[2];
#pragma unroll
    for (int half = 0; half < 2; half++) {
        const float* a = p + half * 128 * stride;
        float r[8];
#pragma unroll
        for (int l = 0; l < 8; l++) {
            float v = a[l * stride];
            float sq = v * v;
            asm volatile("" : "+v"(sq));   // forbid fma contraction
            r[l] = sq;
        }
#pragma unroll
        for (int i = 8; i < 128; i += 8) {
#pragma unroll
            for (int l = 0; l < 8; l++) {
                float v = a[(i + l) * stride];
                float sq = v * v;
                asm volatile("" : "+v"(sq));
                r[l] = r[l] + sq;
            }
        }
        s[half] = ((r[0] + r[1]) + (r[2] + r[3])) + ((r[4] + r[5]) + (r[6] + r[7]));
    }
    return s[0] + s[1];
}

__device__ __forceinline__ unsigned int f32_sortable(float m) {
    unsigned int u = __float_as_uint(m);
    return u ^ (((unsigned int)((int)u >> 31)) | 0x80000000u);
}

__device__ __forceinline__ unsigned short f2bf(float f) {      // RNE float->bf16
    unsigned int u = __float_as_uint(f);
    return (unsigned short)((u + 0x7fffu + ((u >> 16) & 1u)) >> 16);
}
__device__ __forceinline__ float bf2f(unsigned short h) {
    return __uint_as_float(((unsigned int)h) << 16);
}

// ---------------- k0: codebook ||e||^2 (np semantics) + init ----------------
__global__ __launch_bounds__(256) void k0_see(const float* __restrict__ emb,
                                              float* __restrict__ see,
                                              int* __restrict__ cnt,
                                              double* __restrict__ loss) {
    const int k = blockIdx.x * 256 + threadIdx.x;   // grid 4
    see[k] = np_sumsq256(emb + (size_t)k * 256, 1);
    if (k == 0) { *cnt = 0; *loss = 0.0; }
}

// ---------------- k_epack: emb -> MFMA-fragment-packed bf16 hi/lo ----------------
// ebP chunk idx = [codeg(8)][cc(8)][ct(8)][ph(2)][l(64)], 16B per chunk.
__global__ __launch_bounds__(256) void k_epack(const float* __restrict__ emb,
                                               unsigned short* __restrict__ ebP) {
    const int idx = blockIdx.x * 256 + threadIdx.x;   // grid 256 -> 65536 chunks
    const int l  = idx & 63;
    const int ph = (idx >> 6) & 1;
    const int ct = (idx >> 7) & 7;
    const int cc = (idx >> 10) & 7;
    const int cg = (idx >> 13) & 7;
    const int row = cg * 128 + ct * 16 + (l & 15);
    const int col = cc * 32 + (l >> 4) * 8;
    const float* src = emb + (size_t)row * 256 + col;
    uint4 out;
    unsigned short* op = (unsigned short*)&out;
#pragma unroll
    for (int i = 0; i < 8; i++) {
        const float v = src[i];
        const unsigned short h = f2bf(v);
        op[i] = ph ? f2bf(v - bf2f(h)) : h;      // v-h exact (Sterbenz)
    }
    *(uint4*)(ebP + (size_t)idx * 8) = out;
}

// ---------------- k_et: transpose codebook -> eT[c][k] (runs AFTER k1) ----------------
__global__ __launch_bounds__(256) void k_et(const float* __restrict__ emb,
                                            float* __restrict__ eT) {
    __shared__ float T[256][17];
    const int t  = threadIdx.x;
    const int k0 = blockIdx.x << 4;                 // grid 64
    const int kr = t >> 4, cs = (t & 15) << 4;
#pragma unroll
    for (int j = 0; j < 4; j++) {
        const float4 v = *(const float4*)(emb + (size_t)(k0 + kr) * 256 + cs + j * 4);
        T[cs + j * 4 + 0][kr] = v.x;
        T[cs + j * 4 + 1][kr] = v.y;
        T[cs + j * 4 + 2][kr] = v.z;
        T[cs + j * 4 + 3][kr] = v.w;
    }
    __syncthreads();
    float* dst = eT + (size_t)t * 1024 + k0;
#pragma unroll
    for (int j = 0; j < 4; j++) {
        float4 v;
        v.x = T[t][j * 4 + 0]; v.y = T[t][j * 4 + 1];
        v.z = T[t][j * 4 + 2]; v.w = T[t][j * 4 + 3];
        *(float4*)(dst + j * 4) = v;
    }
}

// ---------------- k_xpack: x -> MFMA-fragment-packed bf16 hi/lo + sxx ----------------
__global__ __launch_bounds__(256) void k_xpack(const float* __restrict__ x,
                                               unsigned short* __restrict__ axP,
                                               float* __restrict__ sxx) {
    __shared__ float xs[256 * 33];
    const int t = threadIdx.x, rs = blockIdx.x;     // grid 1024, 32 rows each
    const int row = t & 31, cg = t >> 5;
    const int b = rs >> 5;
    const int hw0 = (rs & 31) << 5;
    const float* xb = x + (size_t)b * 262144 + hw0 + row;
#pragma unroll 4
    for (int cc2 = 0; cc2 < 32; cc2++) {
        const int c = cg * 32 + cc2;
        xs[c * 33 + row] = xb[(size_t)c * 1024];
    }
    __syncthreads();
#pragma unroll
    for (int ii = 0; ii < 4; ii++) {
        const int ci = ii * 256 + t;                // chunk-pair 0..1023
        const int l = ci & 63;
        const int rowg = (ci >> 6) & 1;
        const int cc = ci >> 7;
        const int r = rowg * 16 + (l & 15);
        const int c0 = cc * 32 + (l >> 4) * 8;
        uint4 hp, lp;
        unsigned short* hpp = (unsigned short*)&hp;
        unsigned short* lpp = (unsigned short*)&lp;
#pragma unroll
        for (int i = 0; i < 8; i++) {
            const float v = xs[(c0 + i) * 33 + r];
            const unsigned short h = f2bf(v);
            hpp[i] = h;
            lpp[i] = f2bf(v - bf2f(h));
        }
        const size_t base = ((size_t)rs * 8 + cc) * 2 + rowg;   // [rs][cc][rowg]
        *(uint4*)(axP + ((base * 2 + 0) * 64 + l) * 8) = hp;
        *(uint4*)(axP + ((base * 2 + 1) * 64 + l) * 8) = lp;
    }
    if (t < 32) sxx[rs * 32 + t] = np_sumsq256(xs + t, 33);
}

// ---------------- k1: 3-product bf16 MFMA screen (wide acc: 64 rows/wave) ----------------
// grid 256 x 1024 thr (16 waves, launch_bounds(1024,4) -> ample VGPR budget).
// Block = 128 rows x 1024 codes; wave w: rowg=w>>3 (rows rowg*64..+63 = 4 A-tiles),
// codeg=w&7 (128 codes). acc[4][8] f32x4 = 128 VGPR -- quadruples B-reuse per load
// (round 14: 16-row waves made k1 L2-BW-bound: 2.4 GB B re-reads, MfmaUtil 20%).
// dot_est = xh*eh + xh*el + xl*eh in ONE fp32 acc; margin covers np two-fl
// rounding slop (6.2e-5) + est error (<1e-5). C/D: col=lane&15, row=(lane>>4)*4+j.
__global__ __launch_bounds__(1024, 4) void k1_mfma(
        const unsigned short* __restrict__ axP,
        const unsigned short* __restrict__ ebP,
        const float* __restrict__ see_g,
        unsigned long long* __restrict__ key,
        int* __restrict__ cnt, int* __restrict__ wl) {
    __shared__ unsigned long long lk1[128][8];
    __shared__ float lg1[128][8];
    __shared__ float lg2[128][8];
    const int t = threadIdx.x;
    const int w = t >> 6, l = t & 63;
    const int rowg = w >> 3, codeg = w & 7;
    const int lrow = l >> 4, lcol = l & 15;
    const int rb = blockIdx.x;
    const int n0 = rb * 128;

    float4v acc[4][8];
#pragma unroll
    for (int at = 0; at < 4; at++)
#pragma unroll
        for (int ct = 0; ct < 8; ct++) acc[at][ct] = (float4v){0.f, 0.f, 0.f, 0.f};

#pragma unroll
    for (int cc = 0; cc < 8; cc++) {
        short8v ah[4], al[4];
#pragma unroll
        for (int at = 0; at < 4; at++) {
            const int sub = at >> 1, rowg2 = at & 1;
            const size_t ab = ((((size_t)(rb * 4 + rowg * 2 + sub) * 8 + cc) * 2 + rowg2) * 2)
                              * 512 + (size_t)l * 8;
            ah[at] = *(const short8v*)(axP + ab);
            al[at] = *(const short8v*)(axP + ab + 512);
        }
#pragma unroll
        for (int ct = 0; ct < 8; ct++) {
            const size_t bb = ((((size_t)codeg * 8 + cc) * 8 + ct) * 2) * 512 + (size_t)l * 8;
            const short8v bh = *(const short8v*)(ebP + bb);
            const short8v bl = *(const short8v*)(ebP + bb + 512);
#pragma unroll
            for (int at = 0; at < 4; at++) {
                acc[at][ct] = __builtin_amdgcn_mfma_f32_16x16x32_bf16(ah[at], bh, acc[at][ct], 0, 0, 0);
                acc[at][ct] = __builtin_amdgcn_mfma_f32_16x16x32_bf16(ah[at], bl, acc[at][ct], 0, 0, 0);
                acc[at][ct] = __builtin_amdgcn_mfma_f32_16x16x32_bf16(al[at], bh, acc[at][ct], 0, 0, 0);
            }
        }
    }

    float sv[8];
#pragma unroll
    for (int ct = 0; ct < 8; ct++) sv[ct] = see_g[codeg * 128 + ct * 16 + lcol];

    // per-row top-2 of g = see - 2*dot_est  (sxx is row-constant: order-neutral)
#pragma unroll
    for (int at = 0; at < 4; at++) {
#pragma unroll
        for (int j = 0; j < 4; j++) {
            unsigned long long K1 = ~0ull; float G1 = FLT_BIG, G2 = FLT_BIG;
#pragma unroll
            for (int ct = 0; ct < 8; ct++) {
                const float g = fmaf(-2.f, acc[at][ct][j], sv[ct]);
                const int k = codeg * 128 + ct * 16 + lcol;
                const unsigned long long pk =
                    ((unsigned long long)f32_sortable(g) << 32) | (unsigned int)k;
                if (pk < K1) { G2 = G1; K1 = pk; G1 = g; }
                else         { G2 = fminf(G2, g); }
            }
#pragma unroll
            for (int m = 1; m < 16; m <<= 1) {
                const unsigned long long oK = __shfl_xor(K1, m, 64);
                const float oG1 = __shfl_xor(G1, m, 64);
                const float oG2 = __shfl_xor(G2, m, 64);
                if (oK < K1) { G2 = fminf(oG2, G1); K1 = oK; G1 = oG1; }
                else         { G2 = fminf(G2, oG1); }
            }
            // row within block: rowg*64 + sub*32 + rowg2*16 + lrow*4 + j
            const int rloc = rowg * 64 + (at >> 1) * 32 + (at & 1) * 16 + lrow * 4 + j;
            if (lcol == 0) { lk1[rloc][codeg] = K1; lg1[rloc][codeg] = G1; lg2[rloc][codeg] = G2; }
        }
    }
    __syncthreads();
    if (t < 128) {
        unsigned long long K1 = ~0ull; float G1 = FLT_BIG, G2 = FLT_BIG;
        for (int cg = 0; cg < 8; cg++) {
            const unsigned long long oK = lk1[t][cg];
            const float oG1 = lg1[t][cg], oG2 = lg2[t][cg];
            if (oK < K1) { G2 = fminf(oG2, G1); K1 = oK; G1 = oG1; }
            else         { G2 = fminf(G2, oG1); }
        }
        const int n = n0 + t;
        if (G2 - G1 > MARGIN) { key[n] = K1; }
        else { key[n] = ~0ull; wl[atomicAdd(cnt, 1)] = n; }
    }
}

// ---------------- k2r: np-exact fp32-chain rescan (coalesced via eT) ----------------
__global__ __launch_bounds__(256) void k2r(const float* __restrict__ x,
                                           const float* __restrict__ eT,
                                           const float* __restrict__ see,
                                           const float* __restrict__ sxx,
                                           unsigned long long* __restrict__ key,
                                           const int* __restrict__ cnt,
                                           const int* __restrict__ wl) {
    __shared__ float xs[8][264];
    const int t = threadIdx.x;
    const int total = *cnt;
    for (int base = blockIdx.x * 8; base < total; base += 128 * 8) {
        int nrow[8]; float sx8[8];
#pragma unroll
        for (int r = 0; r < 8; r++) {
            int idx = base + r; if (idx >= total) idx = total - 1;   // benign dup
            const int n = wl[idx];
            nrow[r] = n; sx8[r] = sxx[n];
        }
        __syncthreads();                 // prior batch's xs reads done
#pragma unroll
        for (int r = 0; r < 8; r++) {
            const int n = nrow[r];
            xs[r][t] = x[(size_t)(n >> 10) * 262144 + (size_t)t * 1024 + (n & 1023)];
        }
        __syncthreads();
        float d[8][4];
#pragma unroll
        for (int r = 0; r < 8; r++)
#pragma unroll
            for (int j = 0; j < 4; j++) d[r][j] = 0.f;
#pragma unroll 4
        for (int c = 0; c < 256; c++) {
            float ev[4];
#pragma unroll
            for (int j = 0; j < 4; j++) ev[j] = eT[(size_t)c * 1024 + t + 256 * j];
#pragma unroll
            for (int r = 0; r < 8; r++) {
                const float xv = xs[r][c];
                d[r][0] = fmaf(xv, ev[0], d[r][0]);
                d[r][1] = fmaf(xv, ev[1], d[r][1]);
                d[r][2] = fmaf(xv, ev[2], d[r][2]);
                d[r][3] = fmaf(xv, ev[3], d[r][3]);
            }
        }
#pragma unroll
        for (int r = 0; r < 8; r++) {
            unsigned long long best = ~0ull;
#pragma unroll
            for (int j = 0; j < 4; j++) {
                const float q = fmaf(-2.f, d[r][j], sx8[r]) + see[t + 256 * j];
                const unsigned long long pk =
                    ((unsigned long long)f32_sortable(q) << 32) | (unsigned int)(t + 256 * j);
                best = pk < best ? pk : best;
            }
            atomicMin(&key[nrow[r]], best);
        }
    }
}

// ---------------- k3: gather quantized + loss partials + indices ----------------
__global__ __launch_bounds__(256) void k3_out(const float* __restrict__ x,
                                              const float* __restrict__ emb,
                                              const unsigned long long* __restrict__ key,
                                              float* __restrict__ dout,
                                              double* __restrict__ loss) {
    __shared__ float elds[32][257];
    __shared__ int   idxs[32];
    __shared__ float red[256];
    const int t  = threadIdx.x;
    const int bh = blockIdx.x;
    const int b = bh >> 5, h = bh & 31;
    if (t < 32) idxs[t] = (int)(key[(bh << 5) + t] & 0xffffffffull);
    __syncthreads();
    for (int r = 0; r < 32; r++) elds[r][t] = emb[(size_t)idxs[r] * 256 + t];
    __syncthreads();
    const int w = t & 31, cg = t >> 5;
    const size_t base = (size_t)b * 262144 + (size_t)(h * 32 + w);
    float acc = 0.f;
#pragma unroll 4
    for (int s = 0; s < 32; s++) {
        const int c = (cg << 5) + s;
        const float q  = elds[w][c];
        const float xv = x[base + (size_t)c * 1024];
        dout[base + (size_t)c * 1024] = q;
        const float d = q - xv;
        acc = fmaf(d, d, acc);
    }
    red[t] = acc;
    __syncthreads();
    for (int s = 128; s > 0; s >>= 1) {
        if (t < s) red[t] += red[t + s];
        __syncthreads();
    }
    if (t == 0) atomicAdd(loss, (double)red[0]);
    if (t < 32) dout[IDX_OFF + (bh << 5) + t] = (float)idxs[t];
}

// ---------------- k4: finalize loss ----------------
__global__ void k4_fin(const double* __restrict__ loss, float* __restrict__ dout) {
    dout[LOSS_OFF] = (float)(1.25 * (*loss) / 8388608.0);
}

extern "C" void kernel_launch(void* const* d_in, const int* in_sizes, int n_in,
                              void* d_out, int out_size, void* d_ws, size_t ws_size,
                              hipStream_t stream) {
    const float* x   = (const float*)d_in[0];
    const float* emb = (const float*)d_in[1];
    float* dout = (float*)d_out;
    char* ws = (char*)d_ws;
    float*  see  = (float*)(ws + WS_SEE);
    float*  sxx  = (float*)(ws + WS_SXX);
    unsigned long long* key = (unsigned long long*)(ws + WS_KEY);
    int*    cnt  = (int*)(ws + WS_CNT);
    double* loss = (double*)(ws + WS_LOSS);
    int*    wl   = (int*)(ws + WS_WL);
    unsigned short* ebP = (unsigned short*)(ws + WS_EP);
    float*  eT   = (float*)(ws + WS_EP);      // same region: ebP dead after k1
    // packed A fragments parked in d_out (32 MB), overwritten by k3 later
    unsigned short* axP = (unsigned short*)d_out;

    k0_see <<<4,    256, 0, stream>>>(emb, see, cnt, loss);
    k_epack<<<256,  256, 0, stream>>>(emb, ebP);
    k_xpack<<<1024, 256, 0, stream>>>(x, axP, sxx);
    k1_mfma<<<256, 1024, 0, stream>>>(axP, ebP, see, key, cnt, wl);
    k_et   <<<64,   256, 0, stream>>>(emb, eT);          // overwrites ebP region
    k2r    <<<128,  256, 0, stream>>>(x, eT, see, sxx, key, cnt, wl);
    k3_out <<<1024, 256, 0, stream>>>(x, emb, key, dout, loss);
    k4_fin <<<1,      1, 0, stream>>>(loss, dout);
}

// Round 16
// 205.014 us; speedup vs baseline: 1.7746x; 1.7746x over previous
//
#include <hip/hip_runtime.h>

#define LOSS_OFF 8388608
#define IDX_OFF  8388609

// ws layout (bytes)  (total ~1.58 MB)
#define WS_SEE   0          // float[1024]
#define WS_SXX   4096       // float[32768]   -> 135168
#define WS_KEY   135168     // u64[32768]     -> 397312
#define WS_CNT   397312     // int
#define WS_LOSS  397320     // double
#define WS_WL    397328     // int[32768]     -> 528400
#define WS_EP    528448     // packed E frags (1 MB) during k1; REUSED as eT[c][k] (1 MB) after k1

#define FLT_BIG  3.402823466e+38f
#define MARGIN   1.0e-4f

typedef __attribute__((ext_vector_type(8))) short  short8v;
typedef __attribute__((ext_vector_type(4))) float  float4v;

// numpy pairwise_sum of 256 squared elements, bit-exact (round-2 notes).
__device__ __forceinline__ float np_sumsq256(const float* __restrict__ p, int stride) {
    float s[2];
#pragma unroll
    for (int half = 0; half < 2; half++) {
        const float* a = p + half * 128 * stride;
        float r[8];
#pragma unroll
        for (int l = 0; l < 8; l++) {
            float v = a[l * stride];
            float sq = v * v;
            asm volatile("" : "+v"(sq));   // forbid fma contraction
            r[l] = sq;
        }
#pragma unroll
        for (int i = 8; i < 128; i += 8) {
#pragma unroll
            for (int l = 0; l < 8; l++) {
                float v = a[(i + l) * stride];
                float sq = v * v;
                asm volatile("" : "+v"(sq));
                r[l] = r[l] + sq;
            }
        }
        s[half] = ((r[0] + r[1]) + (r[2] + r[3])) + ((r[4] + r[5]) + (r[6] + r[7]));
    }
    return s[0] + s[1];
}

__device__ __forceinline__ unsigned int f32_sortable(float m) {
    unsigned int u = __float_as_uint(m);
    return u ^ (((unsigned int)((int)u >> 31)) | 0x80000000u);
}

__device__ __forceinline__ unsigned short f2bf(float f) {      // RNE float->bf16
    unsigned int u = __float_as_uint(f);
    return (unsigned short)((u + 0x7fffu + ((u >> 16) & 1u)) >> 16);
}
__device__ __forceinline__ float bf2f(unsigned short h) {
    return __uint_as_float(((unsigned int)h) << 16);
}

// ---------------- k0: codebook ||e||^2 (np semantics) + init ----------------
__global__ __launch_bounds__(256) void k0_see(const float* __restrict__ emb,
                                              float* __restrict__ see,
                                              int* __restrict__ cnt,
                                              double* __restrict__ loss) {
    const int k = blockIdx.x * 256 + threadIdx.x;   // grid 4
    see[k] = np_sumsq256(emb + (size_t)k * 256, 1);
    if (k == 0) { *cnt = 0; *loss = 0.0; }
}

// ---------------- k_epack: emb -> MFMA-fragment-packed bf16 hi/lo ----------------
// ebP chunk idx = [codeg(8)][cc(8)][ct(8)][ph(2)][l(64)], 16B per chunk.
__global__ __launch_bounds__(256) void k_epack(const float* __restrict__ emb,
                                               unsigned short* __restrict__ ebP) {
    const int idx = blockIdx.x * 256 + threadIdx.x;   // grid 256 -> 65536 chunks
    const int l  = idx & 63;
    const int ph = (idx >> 6) & 1;
    const int ct = (idx >> 7) & 7;
    const int cc = (idx >> 10) & 7;
    const int cg = (idx >> 13) & 7;
    const int row = cg * 128 + ct * 16 + (l & 15);
    const int col = cc * 32 + (l >> 4) * 8;
    const float* src = emb + (size_t)row * 256 + col;
    uint4 out;
    unsigned short* op = (unsigned short*)&out;
#pragma unroll
    for (int i = 0; i < 8; i++) {
        const float v = src[i];
        const unsigned short h = f2bf(v);
        op[i] = ph ? f2bf(v - bf2f(h)) : h;      // v-h exact (Sterbenz)
    }
    *(uint4*)(ebP + (size_t)idx * 8) = out;
}

// ---------------- k_et: transpose codebook -> eT[c][k] (runs AFTER k1) ----------------
__global__ __launch_bounds__(256) void k_et(const float* __restrict__ emb,
                                            float* __restrict__ eT) {
    __shared__ float T[256][17];
    const int t  = threadIdx.x;
    const int k0 = blockIdx.x << 4;                 // grid 64
    const int kr = t >> 4, cs = (t & 15) << 4;
#pragma unroll
    for (int j = 0; j < 4; j++) {
        const float4 v = *(const float4*)(emb + (size_t)(k0 + kr) * 256 + cs + j * 4);
        T[cs + j * 4 + 0][kr] = v.x;
        T[cs + j * 4 + 1][kr] = v.y;
        T[cs + j * 4 + 2][kr] = v.z;
        T[cs + j * 4 + 3][kr] = v.w;
    }
    __syncthreads();
    float* dst = eT + (size_t)t * 1024 + k0;
#pragma unroll
    for (int j = 0; j < 4; j++) {
        float4 v;
        v.x = T[t][j * 4 + 0]; v.y = T[t][j * 4 + 1];
        v.z = T[t][j * 4 + 2]; v.w = T[t][j * 4 + 3];
        *(float4*)(dst + j * 4) = v;
    }
}

// ---------------- k_xpack: x -> MFMA-fragment-packed bf16 hi/lo + sxx ----------------
__global__ __launch_bounds__(256) void k_xpack(const float* __restrict__ x,
                                               unsigned short* __restrict__ axP,
                                               float* __restrict__ sxx) {
    __shared__ float xs[256 * 33];
    const int t = threadIdx.x, rs = blockIdx.x;     // grid 1024, 32 rows each
    const int row = t & 31, cg = t >> 5;
    const int b = rs >> 5;
    const int hw0 = (rs & 31) << 5;
    const float* xb = x + (size_t)b * 262144 + hw0 + row;
#pragma unroll 4
    for (int cc2 = 0; cc2 < 32; cc2++) {
        const int c = cg * 32 + cc2;
        xs[c * 33 + row] = xb[(size_t)c * 1024];
    }
    __syncthreads();
#pragma unroll
    for (int ii = 0; ii < 4; ii++) {
        const int ci = ii * 256 + t;                // chunk-pair 0..1023
        const int l = ci & 63;
        const int rowg = (ci >> 6) & 1;
        const int cc = ci >> 7;
        const int r = rowg * 16 + (l & 15);
        const int c0 = cc * 32 + (l >> 4) * 8;
        uint4 hp, lp;
        unsigned short* hpp = (unsigned short*)&hp;
        unsigned short* lpp = (unsigned short*)&lp;
#pragma unroll
        for (int i = 0; i < 8; i++) {
            const float v = xs[(c0 + i) * 33 + r];
            const unsigned short h = f2bf(v);
            hpp[i] = h;
            lpp[i] = f2bf(v - bf2f(h));
        }
        const size_t base = ((size_t)rs * 8 + cc) * 2 + rowg;   // [rs][cc][rowg]
        *(uint4*)(axP + ((base * 2 + 0) * 64 + l) * 8) = hp;
        *(uint4*)(axP + ((base * 2 + 1) * 64 + l) * 8) = lp;
    }
    if (t < 32) sxx[rs * 32 + t] = np_sumsq256(xs + t, 33);
}

// ---------------- k1: 3-product bf16 MFMA screen (64 rows/wave, legal budget) ----------------
// grid 512 x 512 thr (8 waves). __launch_bounds__(512,2): 2 waves/EU min ->
// VGPR budget 256 (round 15's (1024,4) capped at 128 < acc alone -> 631 MB spill).
// Block = 64 rows x ALL 1024 codes; wave w = codeg (128 codes), all waves share
// rows. acc[4][8] f32x4 = 128 VGPR: 4x B-reuse per load (round 14's 16-row waves
// were L2-BW-bound at 2.4 GB B-traffic; now ~0.8 GB ~ 23 us, overlapping the
// ~25 us MFMA floor). A row = n0 + at*16 + (l&15) via rs=rb*2+(at>>1), rowg2=at&1.
// dot_est = xh*eh + xh*el + xl*eh in ONE fp32 acc; margin covers np two-fl
// rounding slop (6.2e-5) + est error (<1e-5). C/D: col=lane&15, row=(lane>>4)*4+j.
__global__ __launch_bounds__(512, 2) void k1_mfma(
        const unsigned short* __restrict__ axP,
        const unsigned short* __restrict__ ebP,
        const float* __restrict__ see_g,
        unsigned long long* __restrict__ key,
        int* __restrict__ cnt, int* __restrict__ wl) {
    __shared__ unsigned long long lk1[64][8];
    __shared__ float lg1[64][8];
    __shared__ float lg2[64][8];
    const int t = threadIdx.x;
    const int codeg = t >> 6, l = t & 63;
    const int lrow = l >> 4, lcol = l & 15;
    const int rb = blockIdx.x;
    const int n0 = rb * 64;

    float4v acc[4][8];
#pragma unroll
    for (int at = 0; at < 4; at++)
#pragma unroll
        for (int ct = 0; ct < 8; ct++) acc[at][ct] = (float4v){0.f, 0.f, 0.f, 0.f};

#pragma unroll
    for (int cc = 0; cc < 8; cc++) {
        short8v ah[4], al[4];
#pragma unroll
        for (int at = 0; at < 4; at++) {
            const size_t ab = ((((size_t)(rb * 2 + (at >> 1)) * 8 + cc) * 2 + (at & 1)) * 2)
                              * 512 + (size_t)l * 8;
            ah[at] = *(const short8v*)(axP + ab);
            al[at] = *(const short8v*)(axP + ab + 512);
        }
#pragma unroll
        for (int ct = 0; ct < 8; ct++) {
            const size_t bb = ((((size_t)codeg * 8 + cc) * 8 + ct) * 2) * 512 + (size_t)l * 8;
            const short8v bh = *(const short8v*)(ebP + bb);
            const short8v bl = *(const short8v*)(ebP + bb + 512);
#pragma unroll
            for (int at = 0; at < 4; at++) {
                acc[at][ct] = __builtin_amdgcn_mfma_f32_16x16x32_bf16(ah[at], bh, acc[at][ct], 0, 0, 0);
                acc[at][ct] = __builtin_amdgcn_mfma_f32_16x16x32_bf16(ah[at], bl, acc[at][ct], 0, 0, 0);
                acc[at][ct] = __builtin_amdgcn_mfma_f32_16x16x32_bf16(al[at], bh, acc[at][ct], 0, 0, 0);
            }
        }
    }

    float sv[8];
#pragma unroll
    for (int ct = 0; ct < 8; ct++) sv[ct] = see_g[codeg * 128 + ct * 16 + lcol];

    // per-row top-2 of g = see - 2*dot_est  (sxx is row-constant: order-neutral)
#pragma unroll
    for (int at = 0; at < 4; at++) {
#pragma unroll
        for (int j = 0; j < 4; j++) {
            unsigned long long K1 = ~0ull; float G1 = FLT_BIG, G2 = FLT_BIG;
#pragma unroll
            for (int ct = 0; ct < 8; ct++) {
                const float g = fmaf(-2.f, acc[at][ct][j], sv[ct]);
                const int k = codeg * 128 + ct * 16 + lcol;
                const unsigned long long pk =
                    ((unsigned long long)f32_sortable(g) << 32) | (unsigned int)k;
                if (pk < K1) { G2 = G1; K1 = pk; G1 = g; }
                else         { G2 = fminf(G2, g); }
            }
#pragma unroll
            for (int m = 1; m < 16; m <<= 1) {
                const unsigned long long oK = __shfl_xor(K1, m, 64);
                const float oG1 = __shfl_xor(G1, m, 64);
                const float oG2 = __shfl_xor(G2, m, 64);
                if (oK < K1) { G2 = fminf(oG2, G1); K1 = oK; G1 = oG1; }
                else         { G2 = fminf(G2, oG1); }
            }
            const int rloc = at * 16 + lrow * 4 + j;     // row within 64-row block
            if (lcol == 0) { lk1[rloc][codeg] = K1; lg1[rloc][codeg] = G1; lg2[rloc][codeg] = G2; }
        }
    }
    __syncthreads();
    if (t < 64) {
        unsigned long long K1 = ~0ull; float G1 = FLT_BIG, G2 = FLT_BIG;
        for (int cg = 0; cg < 8; cg++) {
            const unsigned long long oK = lk1[t][cg];
            const float oG1 = lg1[t][cg], oG2 = lg2[t][cg];
            if (oK < K1) { G2 = fminf(oG2, G1); K1 = oK; G1 = oG1; }
            else         { G2 = fminf(G2, oG1); }
        }
        const int n = n0 + t;
        if (G2 - G1 > MARGIN) { key[n] = K1; }
        else { key[n] = ~0ull; wl[atomicAdd(cnt, 1)] = n; }
    }
}

// ---------------- k2r: np-exact fp32-chain rescan (coalesced via eT) ----------------
__global__ __launch_bounds__(256) void k2r(const float* __restrict__ x,
                                           const float* __restrict__ eT,
                                           const float* __restrict__ see,
                                           const float* __restrict__ sxx,
                                           unsigned long long* __restrict__ key,
                                           const int* __restrict__ cnt,
                                           const int* __restrict__ wl) {
    __shared__ float xs[8][264];
    const int t = threadIdx.x;
    const int total = *cnt;
    for (int base = blockIdx.x * 8; base < total; base += 128 * 8) {
        int nrow[8]; float sx8[8];
#pragma unroll
        for (int r = 0; r < 8; r++) {
            int idx = base + r; if (idx >= total) idx = total - 1;   // benign dup
            const int n = wl[idx];
            nrow[r] = n; sx8[r] = sxx[n];
        }
        __syncthreads();                 // prior batch's xs reads done
#pragma unroll
        for (int r = 0; r < 8; r++) {
            const int n = nrow[r];
            xs[r][t] = x[(size_t)(n >> 10) * 262144 + (size_t)t * 1024 + (n & 1023)];
        }
        __syncthreads();
        float d[8][4];
#pragma unroll
        for (int r = 0; r < 8; r++)
#pragma unroll
            for (int j = 0; j < 4; j++) d[r][j] = 0.f;
#pragma unroll 4
        for (int c = 0; c < 256; c++) {
            float ev[4];
#pragma unroll
            for (int j = 0; j < 4; j++) ev[j] = eT[(size_t)c * 1024 + t + 256 * j];
#pragma unroll
            for (int r = 0; r < 8; r++) {
                const float xv = xs[r][c];
                d[r][0] = fmaf(xv, ev[0], d[r][0]);
                d[r][1] = fmaf(xv, ev[1], d[r][1]);
                d[r][2] = fmaf(xv, ev[2], d[r][2]);
                d[r][3] = fmaf(xv, ev[3], d[r][3]);
            }
        }
#pragma unroll
        for (int r = 0; r < 8; r++) {
            unsigned long long best = ~0ull;
#pragma unroll
            for (int j = 0; j < 4; j++) {
                const float q = fmaf(-2.f, d[r][j], sx8[r]) + see[t + 256 * j];
                const unsigned long long pk =
                    ((unsigned long long)f32_sortable(q) << 32) | (unsigned int)(t + 256 * j);
                best = pk < best ? pk : best;
            }
            atomicMin(&key[nrow[r]], best);
        }
    }
}

// ---------------- k3: gather quantized + loss partials + indices ----------------
__global__ __launch_bounds__(256) void k3_out(const float* __restrict__ x,
                                              const float* __restrict__ emb,
                                              const unsigned long long* __restrict__ key,
                                              float* __restrict__ dout,
                                              double* __restrict__ loss) {
    __shared__ float elds[32][257];
    __shared__ int   idxs[32];
    __shared__ float red[256];
    const int t  = threadIdx.x;
    const int bh = blockIdx.x;
    const int b = bh >> 5, h = bh & 31;
    if (t < 32) idxs[t] = (int)(key[(bh << 5) + t] & 0xffffffffull);
    __syncthreads();
    for (int r = 0; r < 32; r++) elds[r][t] = emb[(size_t)idxs[r] * 256 + t];
    __syncthreads();
    const int w = t & 31, cg = t >> 5;
    const size_t base = (size_t)b * 262144 + (size_t)(h * 32 + w);
    float acc = 0.f;
#pragma unroll 4
    for (int s = 0; s < 32; s++) {
        const int c = (cg << 5) + s;
        const float q  = elds[w][c];
        const float xv = x[base + (size_t)c * 1024];
        dout[base + (size_t)c * 1024] = q;
        const float d = q - xv;
        acc = fmaf(d, d, acc);
    }
    red[t] = acc;
    __syncthreads();
    for (int s = 128; s > 0; s >>= 1) {
        if (t < s) red[t] += red[t + s];
        __syncthreads();
    }
    if (t == 0) atomicAdd(loss, (double)red[0]);
    if (t < 32) dout[IDX_OFF + (bh << 5) + t] = (float)idxs[t];
}

// ---------------- k4: finalize loss ----------------
__global__ void k4_fin(const double* __restrict__ loss, float* __restrict__ dout) {
    dout[LOSS_OFF] = (float)(1.25 * (*loss) / 8388608.0);
}

extern "C" void kernel_launch(void* const* d_in, const int* in_sizes, int n_in,
                              void* d_out, int out_size, void* d_ws, size_t ws_size,
                              hipStream_t stream) {
    const float* x   = (const float*)d_in[0];
    const float* emb = (const float*)d_in[1];
    float* dout = (float*)d_out;
    char* ws = (char*)d_ws;
    float*  see  = (float*)(ws + WS_SEE);
    float*  sxx  = (float*)(ws + WS_SXX);
    unsigned long long* key = (unsigned long long*)(ws + WS_KEY);
    int*    cnt  = (int*)(ws + WS_CNT);
    double* loss = (double*)(ws + WS_LOSS);
    int*    wl   = (int*)(ws + WS_WL);
    unsigned short* ebP = (unsigned short*)(ws + WS_EP);
    float*  eT   = (float*)(ws + WS_EP);      // same region: ebP dead after k1
    // packed A fragments parked in d_out (32 MB), overwritten by k3 later
    unsigned short* axP = (unsigned short*)d_out;

    k0_see <<<4,    256, 0, stream>>>(emb, see, cnt, loss);
    k_epack<<<256,  256, 0, stream>>>(emb, ebP);
    k_xpack<<<1024, 256, 0, stream>>>(x, axP, sxx);
    k1_mfma<<<512,  512, 0, stream>>>(axP, ebP, see, key, cnt, wl);
    k_et   <<<64,   256, 0, stream>>>(emb, eT);          // overwrites ebP region
    k2r    <<<128,  256, 0, stream>>>(x, eT, see, sxx, key, cnt, wl);
    k3_out <<<1024, 256, 0, stream>>>(x, emb, key, dout, loss);
    k4_fin <<<1,      1, 0, stream>>>(loss, dout);
}

// Round 17
// 204.622 us; speedup vs baseline: 1.7780x; 1.0019x over previous
//
#include <hip/hip_runtime.h>

#define LOSS_OFF 8388608
#define IDX_OFF  8388609

// ws layout (bytes)  (total ~1.58 MB)
#define WS_SEE   0          // float[1024]
#define WS_SXX   4096       // float[32768]   -> 135168
#define WS_KEY   135168     // u64[32768]     -> 397312
#define WS_CNT   397312     // int
#define WS_LOSS  397320     // double
#define WS_WL    397328     // int[32768]     -> 528400
#define WS_EP    528448     // packed E frags (1 MB) during k1; REUSED as eT[c][k] (1 MB) after k1

#define FLT_BIG  3.402823466e+38f
#define MARGIN   1.0e-4f

typedef __attribute__((ext_vector_type(8))) short  short8v;
typedef __attribute__((ext_vector_type(4))) float  float4v;

// async global->LDS, 16B per lane; LDS dest = wave-uniform base + lane*16
#define GLD16(gp, lp) __builtin_amdgcn_global_load_lds( \
    (const __attribute__((address_space(1))) unsigned int*)(gp), \
    (__attribute__((address_space(3))) unsigned int*)(lp), 16, 0, 0)

// numpy pairwise_sum of 256 squared elements, bit-exact (round-2 notes).
__device__ __forceinline__ float np_sumsq256(const float* __restrict__ p, int stride) {
    float s[2];
#pragma unroll
    for (int half = 0; half < 2; half++) {
        const float* a = p + half * 128 * stride;
        float r[8];
#pragma unroll
        for (int l = 0; l < 8; l++) {
            float v = a[l * stride];
            float sq = v * v;
            asm volatile("" : "+v"(sq));   // forbid fma contraction
            r[l] = sq;
        }
#pragma unroll
        for (int i = 8; i < 128; i += 8) {
#pragma unroll
            for (int l = 0; l < 8; l++) {
                float v = a[(i + l) * stride];
                float sq = v * v;
                asm volatile("" : "+v"(sq));
                r[l] = r[l] + sq;
            }
        }
        s[half] = ((r[0] + r[1]) + (r[2] + r[3])) + ((r[4] + r[5]) + (r[6] + r[7]));
    }
    return s[0] + s[1];
}

__device__ __forceinline__ unsigned int f32_sortable(float m) {
    unsigned int u = __float_as_uint(m);
    return u ^ (((unsigned int)((int)u >> 31)) | 0x80000000u);
}
__device__ __forceinline__ float f32_unsortable(unsigned int s) {   // inverse
    const unsigned int u = (s >> 31) ? (s ^ 0x80000000u) : ~s;
    return __uint_as_float(u);
}

__device__ __forceinline__ unsigned short f2bf(float f) {      // RNE float->bf16
    unsigned int u = __float_as_uint(f);
    return (unsigned short)((u + 0x7fffu + ((u >> 16) & 1u)) >> 16);
}
__device__ __forceinline__ float bf2f(unsigned short h) {
    return __uint_as_float(((unsigned int)h) << 16);
}

// ---------------- k_prep: epack (blocks 0..255) + see/init (blocks 256..259) ----------------
// ebP chunk idx = [codeg(8)][cc(8)][ct(8)][ph(2)][l(64)], 16B per chunk.
__global__ __launch_bounds__(256) void k_prep(const float* __restrict__ emb,
                                              unsigned short* __restrict__ ebP,
                                              float* __restrict__ see,
                                              int* __restrict__ cnt,
                                              double* __restrict__ loss) {
    const int t = threadIdx.x, bb = blockIdx.x;
    if (bb < 256) {
        const int idx = bb * 256 + t;
        const int l  = idx & 63;
        const int ph = (idx >> 6) & 1;
        const int ct = (idx >> 7) & 7;
        const int cc = (idx >> 10) & 7;
        const int cg = (idx >> 13) & 7;
        const int row = cg * 128 + ct * 16 + (l & 15);
        const int col = cc * 32 + (l >> 4) * 8;
        const float* src = emb + (size_t)row * 256 + col;
        uint4 out;
        unsigned short* op = (unsigned short*)&out;
#pragma unroll
        for (int i = 0; i < 8; i++) {
            const float v = src[i];
            const unsigned short h = f2bf(v);
            op[i] = ph ? f2bf(v - bf2f(h)) : h;      // v-h exact (Sterbenz)
        }
        *(uint4*)(ebP + (size_t)idx * 8) = out;
    } else {
        const int k = (bb - 256) * 256 + t;
        see[k] = np_sumsq256(emb + (size_t)k * 256, 1);
        if (k == 0) { *cnt = 0; *loss = 0.0; }
    }
}

// ---------------- k_et: transpose codebook -> eT[c][k] (runs AFTER k1) ----------------
__global__ __launch_bounds__(256) void k_et(const float* __restrict__ emb,
                                            float* __restrict__ eT) {
    __shared__ float T[256][17];
    const int t  = threadIdx.x;
    const int k0 = blockIdx.x << 4;                 // grid 64
    const int kr = t >> 4, cs = (t & 15) << 4;
#pragma unroll
    for (int j = 0; j < 4; j++) {
        const float4 v = *(const float4*)(emb + (size_t)(k0 + kr) * 256 + cs + j * 4);
        T[cs + j * 4 + 0][kr] = v.x;
        T[cs + j * 4 + 1][kr] = v.y;
        T[cs + j * 4 + 2][kr] = v.z;
        T[cs + j * 4 + 3][kr] = v.w;
    }
    __syncthreads();
    float* dst = eT + (size_t)t * 1024 + k0;
#pragma unroll
    for (int j = 0; j < 4; j++) {
        float4 v;
        v.x = T[t][j * 4 + 0]; v.y = T[t][j * 4 + 1];
        v.z = T[t][j * 4 + 2]; v.w = T[t][j * 4 + 3];
        *(float4*)(dst + j * 4) = v;
    }
}

// ---------------- k_xpack: x -> MFMA-fragment-packed bf16 hi/lo + sxx ----------------
__global__ __launch_bounds__(256) void k_xpack(const float* __restrict__ x,
                                               unsigned short* __restrict__ axP,
                                               float* __restrict__ sxx) {
    __shared__ float xs[256 * 33];
    const int t = threadIdx.x, rs = blockIdx.x;     // grid 1024, 32 rows each
    const int row = t & 31, cg = t >> 5;
    const int b = rs >> 5;
    const int hw0 = (rs & 31) << 5;
    const float* xb = x + (size_t)b * 262144 + hw0 + row;
#pragma unroll 4
    for (int cc2 = 0; cc2 < 32; cc2++) {
        const int c = cg * 32 + cc2;
        xs[c * 33 + row] = xb[(size_t)c * 1024];
    }
    __syncthreads();
#pragma unroll
    for (int ii = 0; ii < 4; ii++) {
        const int ci = ii * 256 + t;                // chunk-pair 0..1023
        const int l = ci & 63;
        const int rowg = (ci >> 6) & 1;
        const int cc = ci >> 7;
        const int r = rowg * 16 + (l & 15);
        const int c0 = cc * 32 + (l >> 4) * 8;
        uint4 hp, lp;
        unsigned short* hpp = (unsigned short*)&hp;
        unsigned short* lpp = (unsigned short*)&lp;
#pragma unroll
        for (int i = 0; i < 8; i++) {
            const float v = xs[(c0 + i) * 33 + r];
            const unsigned short h = f2bf(v);
            hpp[i] = h;
            lpp[i] = f2bf(v - bf2f(h));
        }
        const size_t base = ((size_t)rs * 8 + cc) * 2 + rowg;   // [rs][cc][rowg]
        *(uint4*)(axP + ((base * 2 + 0) * 64 + l) * 8) = hp;
        *(uint4*)(axP + ((base * 2 + 1) * 64 + l) * 8) = lp;
    }
    if (t < 32) sxx[rs * 32 + t] = np_sumsq256(xs + t, 33);
}

// ---------------- k1: 3-product bf16 MFMA screen (LDS-shared A, light fold) ----------------
// grid 512 x 512 thr (8 waves, launch_bounds(512,2) -> 256-reg budget, no spill).
// Block = 64 rows x ALL 1024 codes; wave w = codeg. acc[4][8] f32x4 = 128 AGPR.
// A (8 KB/cc) is identical for all 8 waves -> staged ONCE via global_load_lds
// (1 instr/thread), waves ds_read_b128 fragments (2-way banks = free). Cuts A
// L2 traffic 8x and frees global-issue slots (round 16: additive 21+18+28us
// phases, A-loads+fold on the critical path).
// Fold: G1 == unsortable(K1>>32) (bijective map) -> shuffle only K1+G2
// (3 permutes/step vs 5), no lg1 LDS array.
// dot_est = xh*eh + xh*el + xl*eh in ONE fp32 acc; margin covers np two-fl
// rounding slop (6.2e-5) + est error (<1e-5). C/D: col=lane&15, row=(lane>>4)*4+j.
__global__ __launch_bounds__(512, 2) void k1_mfma(
        const unsigned short* __restrict__ axP,
        const unsigned short* __restrict__ ebP,
        const float* __restrict__ see_g,
        unsigned long long* __restrict__ key,
        int* __restrict__ cnt, int* __restrict__ wl) {
    __shared__ char smem[8192];     // A-stage (main loop) ALIASED with reduce arrays (post-loop)
    unsigned long long* lk1 = (unsigned long long*)smem;   // [64][8] = 4 KB
    float*              lg2 = (float*)(smem + 4096);       // [64][8] = 2 KB
    const int t = threadIdx.x;
    const int codeg = t >> 6, l = t & 63;
    const int lrow = l >> 4, lcol = l & 15;
    const int rb = blockIdx.x;
    const int n0 = rb * 64;
    const char* aBase = (const char*)axP;
    char* aDst = smem + codeg * 1024;               // wave-uniform LDS dest

    float4v acc[4][8];
#pragma unroll
    for (int at = 0; at < 4; at++)
#pragma unroll
        for (int ct = 0; ct < 8; ct++) acc[at][ct] = (float4v){0.f, 0.f, 0.f, 0.f};

    for (int cc = 0; cc < 8; cc++) {
        __syncthreads();                            // prior cc's A ds_reads done
        // stage A (8 KB): [sub][rowg2][ph][l*16B]; thread t stages byte t*16.
        // src region for (rs=rb*2+sub, cc) = 4 KB contiguous at (rs*8+cc)*4096.
        {
            const int sub = codeg >> 2;
            const char* src = aBase + ((size_t)((rb * 2 + sub) * 8 + cc)) * 4096
                              + (size_t)(codeg & 3) * 1024 + (size_t)l * 16;
            GLD16(src, aDst);
        }
        __syncthreads();                            // drains vmcnt -> A in LDS
        short8v ah[4], al[4];
#pragma unroll
        for (int at = 0; at < 4; at++) {
            const int off = (at >> 1) * 4096 + (at & 1) * 2048;
            ah[at] = *(const short8v*)(smem + off + l * 16);
            al[at] = *(const short8v*)(smem + off + 1024 + l * 16);
        }
#pragma unroll
        for (int ct = 0; ct < 8; ct++) {
            const size_t bb = ((((size_t)codeg * 8 + cc) * 8 + ct) * 2) * 512 + (size_t)l * 8;
            const short8v bh = *(const short8v*)(ebP + bb);
            const short8v bl = *(const short8v*)(ebP + bb + 512);
#pragma unroll
            for (int at = 0; at < 4; at++) {
                acc[at][ct] = __builtin_amdgcn_mfma_f32_16x16x32_bf16(ah[at], bh, acc[at][ct], 0, 0, 0);
                acc[at][ct] = __builtin_amdgcn_mfma_f32_16x16x32_bf16(ah[at], bl, acc[at][ct], 0, 0, 0);
                acc[at][ct] = __builtin_amdgcn_mfma_f32_16x16x32_bf16(al[at], bh, acc[at][ct], 0, 0, 0);
            }
        }
    }
    __syncthreads();                                // last A reads done before alias reuse

    float sv[8];
#pragma unroll
    for (int ct = 0; ct < 8; ct++) sv[ct] = see_g[codeg * 128 + ct * 16 + lcol];

    // per-row top-2 of g = see - 2*dot_est  (sxx row-constant: order-neutral)
#pragma unroll
    for (int at = 0; at < 4; at++) {
#pragma unroll
        for (int j = 0; j < 4; j++) {
            unsigned long long K1 = ~0ull; float G1 = FLT_BIG, G2 = FLT_BIG;
#pragma unroll
            for (int ct = 0; ct < 8; ct++) {
                const float g = fmaf(-2.f, acc[at][ct][j], sv[ct]);
                const int k = codeg * 128 + ct * 16 + lcol;
                const unsigned long long pk =
                    ((unsigned long long)f32_sortable(g) << 32) | (unsigned int)k;
                if (pk < K1) { G2 = G1; K1 = pk; G1 = g; }
                else         { G2 = fminf(G2, g); }
            }
#pragma unroll
            for (int m = 1; m < 16; m <<= 1) {
                const unsigned long long oK = __shfl_xor(K1, m, 64);
                const float oG2 = __shfl_xor(G2, m, 64);
                const float oG1 = f32_unsortable((unsigned int)(oK >> 32));
                if (oK < K1) { G2 = fminf(oG2, G1); K1 = oK; G1 = oG1; }
                else         { G2 = fminf(G2, oG1); }
            }
            const int rloc = at * 16 + lrow * 4 + j;     // row within 64-row block
            if (lcol == 0) { lk1[rloc * 8 + codeg] = K1; lg2[rloc * 8 + codeg] = G2; }
        }
    }
    __syncthreads();
    if (t < 64) {
        unsigned long long K1 = ~0ull; float G1 = FLT_BIG, G2 = FLT_BIG;
        for (int cg = 0; cg < 8; cg++) {
            const unsigned long long oK = lk1[t * 8 + cg];
            const float oG2 = lg2[t * 8 + cg];
            const float oG1 = f32_unsortable((unsigned int)(oK >> 32));
            if (oK < K1) { G2 = fminf(oG2, G1); K1 = oK; G1 = oG1; }
            else         { G2 = fminf(G2, oG1); }
        }
        const int n = n0 + t;
        if (G2 - G1 > MARGIN) { key[n] = K1; }
        else { key[n] = ~0ull; wl[atomicAdd(cnt, 1)] = n; }
    }
}

// ---------------- k2r: np-exact fp32-chain rescan (coalesced via eT) ----------------
__global__ __launch_bounds__(256) void k2r(const float* __restrict__ x,
                                           const float* __restrict__ eT,
                                           const float* __restrict__ see,
                                           const float* __restrict__ sxx,
                                           unsigned long long* __restrict__ key,
                                           const int* __restrict__ cnt,
                                           const int* __restrict__ wl) {
    __shared__ float xs[8][264];
    const int t = threadIdx.x;
    const int total = *cnt;
    for (int base = blockIdx.x * 8; base < total; base += 128 * 8) {
        int nrow[8]; float sx8[8];
#pragma unroll
        for (int r = 0; r < 8; r++) {
            int idx = base + r; if (idx >= total) idx = total - 1;   // benign dup
            const int n = wl[idx];
            nrow[r] = n; sx8[r] = sxx[n];
        }
        __syncthreads();                 // prior batch's xs reads done
#pragma unroll
        for (int r = 0; r < 8; r++) {
            const int n = nrow[r];
            xs[r][t] = x[(size_t)(n >> 10) * 262144 + (size_t)t * 1024 + (n & 1023)];
        }
        __syncthreads();
        float d[8][4];
#pragma unroll
        for (int r = 0; r < 8; r++)
#pragma unroll
            for (int j = 0; j < 4; j++) d[r][j] = 0.f;
#pragma unroll 4
        for (int c = 0; c < 256; c++) {
            float ev[4];
#pragma unroll
            for (int j = 0; j < 4; j++) ev[j] = eT[(size_t)c * 1024 + t + 256 * j];
#pragma unroll
            for (int r = 0; r < 8; r++) {
                const float xv = xs[r][c];
                d[r][0] = fmaf(xv, ev[0], d[r][0]);
                d[r][1] = fmaf(xv, ev[1], d[r][1]);
                d[r][2] = fmaf(xv, ev[2], d[r][2]);
                d[r][3] = fmaf(xv, ev[3], d[r][3]);
            }
        }
#pragma unroll
        for (int r = 0; r < 8; r++) {
            unsigned long long best = ~0ull;
#pragma unroll
            for (int j = 0; j < 4; j++) {
                const float q = fmaf(-2.f, d[r][j], sx8[r]) + see[t + 256 * j];
                const unsigned long long pk =
                    ((unsigned long long)f32_sortable(q) << 32) | (unsigned int)(t + 256 * j);
                best = pk < best ? pk : best;
            }
            atomicMin(&key[nrow[r]], best);
        }
    }
}

// ---------------- k3: gather quantized + loss partials + indices ----------------
__global__ __launch_bounds__(256) void k3_out(const float* __restrict__ x,
                                              const float* __restrict__ emb,
                                              const unsigned long long* __restrict__ key,
                                              float* __restrict__ dout,
                                              double* __restrict__ loss) {
    __shared__ float elds[32][257];
    __shared__ int   idxs[32];
    __shared__ float red[256];
    const int t  = threadIdx.x;
    const int bh = blockIdx.x;
    const int b = bh >> 5, h = bh & 31;
    if (t < 32) idxs[t] = (int)(key[(bh << 5) + t] & 0xffffffffull);
    __syncthreads();
    for (int r = 0; r < 32; r++) elds[r][t] = emb[(size_t)idxs[r] * 256 + t];
    __syncthreads();
    const int w = t & 31, cg = t >> 5;
    const size_t base = (size_t)b * 262144 + (size_t)(h * 32 + w);
    float acc = 0.f;
#pragma unroll 4
    for (int s = 0; s < 32; s++) {
        const int c = (cg << 5) + s;
        const float q  = elds[w][c];
        const float xv = x[base + (size_t)c * 1024];
        dout[base + (size_t)c * 1024] = q;
        const float d = q - xv;
        acc = fmaf(d, d, acc);
    }
    red[t] = acc;
    __syncthreads();
    for (int s = 128; s > 0; s >>= 1) {
        if (t < s) red[t] += red[t + s];
        __syncthreads();
    }
    if (t == 0) atomicAdd(loss, (double)red[0]);
    if (t < 32) dout[IDX_OFF + (bh << 5) + t] = (float)idxs[t];
}

// ---------------- k4: finalize loss ----------------
__global__ void k4_fin(const double* __restrict__ loss, float* __restrict__ dout) {
    dout[LOSS_OFF] = (float)(1.25 * (*loss) / 8388608.0);
}

extern "C" void kernel_launch(void* const* d_in, const int* in_sizes, int n_in,
                              void* d_out, int out_size, void* d_ws, size_t ws_size,
                              hipStream_t stream) {
    const float* x   = (const float*)d_in[0];
    const float* emb = (const float*)d_in[1];
    float* dout = (float*)d_out;
    char* ws = (char*)d_ws;
    float*  see  = (float*)(ws + WS_SEE);
    float*  sxx  = (float*)(ws + WS_SXX);
    unsigned long long* key = (unsigned long long*)(ws + WS_KEY);
    int*    cnt  = (int*)(ws + WS_CNT);
    double* loss = (double*)(ws + WS_LOSS);
    int*    wl   = (int*)(ws + WS_WL);
    unsigned short* ebP = (unsigned short*)(ws + WS_EP);
    float*  eT   = (float*)(ws + WS_EP);      // same region: ebP dead after k1
    // packed A fragments parked in d_out (32 MB), overwritten by k3 later
    unsigned short* axP = (unsigned short*)d_out;

    k_prep <<<260,  256, 0, stream>>>(emb, ebP, see, cnt, loss);
    k_xpack<<<1024, 256, 0, stream>>>(x, axP, sxx);
    k1_mfma<<<512,  512, 0, stream>>>(axP, ebP, see, key, cnt, wl);
    k_et   <<<64,   256, 0, stream>>>(emb, eT);          // overwrites ebP region
    k2r    <<<128,  256, 0, stream>>>(x, eT, see, sxx, key, cnt, wl);
    k3_out <<<1024, 256, 0, stream>>>(x, emb, key, dout, loss);
    k4_fin <<<1,      1, 0, stream>>>(loss, dout);
}

// Round 18
// 199.968 us; speedup vs baseline: 1.8194x; 1.0233x over previous
//
#include <hip/hip_runtime.h>

#define LOSS_OFF 8388608
#define IDX_OFF  8388609

// ws layout (bytes)  (total ~1.58 MB)
#define WS_SEE   0          // float[1024]
#define WS_SXX   4096       // float[32768]   -> 135168
#define WS_KEY   135168     // u64[32768]     -> 397312
#define WS_CNT   397312     // int
#define WS_LOSS  397320     // double
#define WS_WL    397328     // int[32768]     -> 528400
#define WS_EP    528448     // packed E frags (1 MB) during k1; REUSED as eT[c][k] (1 MB) after k1

#define FLT_BIG  3.402823466e+38f
#define MARGIN   1.0e-4f

typedef __attribute__((ext_vector_type(8))) short  short8v;
typedef __attribute__((ext_vector_type(4))) float  float4v;

// async global->LDS, 16B per lane; LDS dest = wave-uniform base + lane*16
#define GLD16(gp, lp) __builtin_amdgcn_global_load_lds( \
    (const __attribute__((address_space(1))) unsigned int*)(gp), \
    (__attribute__((address_space(3))) unsigned int*)(lp), 16, 0, 0)

// numpy pairwise_sum of 256 squared elements, bit-exact (round-2 notes).
__device__ __forceinline__ float np_sumsq256(const float* __restrict__ p, int stride) {
    float s[2];
#pragma unroll
    for (int half = 0; half < 2; half++) {
        const float* a = p + half * 128 * stride;
        float r[8];
#pragma unroll
        for (int l = 0; l < 8; l++) {
            float v = a[l * stride];
            float sq = v * v;
            asm volatile("" : "+v"(sq));   // forbid fma contraction
            r[l] = sq;
        }
#pragma unroll
        for (int i = 8; i < 128; i += 8) {
#pragma unroll
            for (int l = 0; l < 8; l++) {
                float v = a[(i + l) * stride];
                float sq = v * v;
                asm volatile("" : "+v"(sq));
                r[l] = r[l] + sq;
            }
        }
        s[half] = ((r[0] + r[1]) + (r[2] + r[3])) + ((r[4] + r[5]) + (r[6] + r[7]));
    }
    return s[0] + s[1];
}

__device__ __forceinline__ unsigned int f32_sortable(float m) {
    unsigned int u = __float_as_uint(m);
    return u ^ (((unsigned int)((int)u >> 31)) | 0x80000000u);
}
__device__ __forceinline__ float f32_unsortable(unsigned int s) {   // inverse
    const unsigned int u = (s >> 31) ? (s ^ 0x80000000u) : ~s;
    return __uint_as_float(u);
}

__device__ __forceinline__ unsigned short f2bf(float f) {      // RNE float->bf16
    unsigned int u = __float_as_uint(f);
    return (unsigned short)((u + 0x7fffu + ((u >> 16) & 1u)) >> 16);
}
__device__ __forceinline__ float bf2f(unsigned short h) {
    return __uint_as_float(((unsigned int)h) << 16);
}

// ---------------- k_prep: epack (blocks 0..255) + see/init (blocks 256..259) ----------------
// ebP chunk idx = [codeg(8)][cc(8)][ct(8)][ph(2)][l(64)], 16B per chunk.
__global__ __launch_bounds__(256) void k_prep(const float* __restrict__ emb,
                                              unsigned short* __restrict__ ebP,
                                              float* __restrict__ see,
                                              int* __restrict__ cnt,
                                              double* __restrict__ loss) {
    const int t = threadIdx.x, bb = blockIdx.x;
    if (bb < 256) {
        const int idx = bb * 256 + t;
        const int l  = idx & 63;
        const int ph = (idx >> 6) & 1;
        const int ct = (idx >> 7) & 7;
        const int cc = (idx >> 10) & 7;
        const int cg = (idx >> 13) & 7;
        const int row = cg * 128 + ct * 16 + (l & 15);
        const int col = cc * 32 + (l >> 4) * 8;
        const float* src = emb + (size_t)row * 256 + col;
        uint4 out;
        unsigned short* op = (unsigned short*)&out;
#pragma unroll
        for (int i = 0; i < 8; i++) {
            const float v = src[i];
            const unsigned short h = f2bf(v);
            op[i] = ph ? f2bf(v - bf2f(h)) : h;      // v-h exact (Sterbenz)
        }
        *(uint4*)(ebP + (size_t)idx * 8) = out;
    } else {
        const int k = (bb - 256) * 256 + t;
        see[k] = np_sumsq256(emb + (size_t)k * 256, 1);
        if (k == 0) { *cnt = 0; *loss = 0.0; }
    }
}

// ---------------- k_et: transpose codebook -> eT[c][k] (runs AFTER k1) ----------------
__global__ __launch_bounds__(256) void k_et(const float* __restrict__ emb,
                                            float* __restrict__ eT) {
    __shared__ float T[256][17];
    const int t  = threadIdx.x;
    const int k0 = blockIdx.x << 4;                 // grid 64
    const int kr = t >> 4, cs = (t & 15) << 4;
#pragma unroll
    for (int j = 0; j < 4; j++) {
        const float4 v = *(const float4*)(emb + (size_t)(k0 + kr) * 256 + cs + j * 4);
        T[cs + j * 4 + 0][kr] = v.x;
        T[cs + j * 4 + 1][kr] = v.y;
        T[cs + j * 4 + 2][kr] = v.z;
        T[cs + j * 4 + 3][kr] = v.w;
    }
    __syncthreads();
    float* dst = eT + (size_t)t * 1024 + k0;
#pragma unroll
    for (int j = 0; j < 4; j++) {
        float4 v;
        v.x = T[t][j * 4 + 0]; v.y = T[t][j * 4 + 1];
        v.z = T[t][j * 4 + 2]; v.w = T[t][j * 4 + 3];
        *(float4*)(dst + j * 4) = v;
    }
}

// ---------------- k_xpack: x -> MFMA-fragment-packed bf16 hi/lo + sxx ----------------
__global__ __launch_bounds__(256) void k_xpack(const float* __restrict__ x,
                                               unsigned short* __restrict__ axP,
                                               float* __restrict__ sxx) {
    __shared__ float xs[256 * 33];
    const int t = threadIdx.x, rs = blockIdx.x;     // grid 1024, 32 rows each
    const int row = t & 31, cg = t >> 5;
    const int b = rs >> 5;
    const int hw0 = (rs & 31) << 5;
    const float* xb = x + (size_t)b * 262144 + hw0 + row;
#pragma unroll 4
    for (int cc2 = 0; cc2 < 32; cc2++) {
        const int c = cg * 32 + cc2;
        xs[c * 33 + row] = xb[(size_t)c * 1024];
    }
    __syncthreads();
#pragma unroll
    for (int ii = 0; ii < 4; ii++) {
        const int ci = ii * 256 + t;                // chunk-pair 0..1023
        const int l = ci & 63;
        const int rowg = (ci >> 6) & 1;
        const int cc = ci >> 7;
        const int r = rowg * 16 + (l & 15);
        const int c0 = cc * 32 + (l >> 4) * 8;
        uint4 hp, lp;
        unsigned short* hpp = (unsigned short*)&hp;
        unsigned short* lpp = (unsigned short*)&lp;
#pragma unroll
        for (int i = 0; i < 8; i++) {
            const float v = xs[(c0 + i) * 33 + r];
            const unsigned short h = f2bf(v);
            hpp[i] = h;
            lpp[i] = f2bf(v - bf2f(h));
        }
        const size_t base = ((size_t)rs * 8 + cc) * 2 + rowg;   // [rs][cc][rowg]
        *(uint4*)(axP + ((base * 2 + 0) * 64 + l) * 8) = hp;
        *(uint4*)(axP + ((base * 2 + 1) * 64 + l) * 8) = lp;
    }
    if (t < 32) sxx[rs * 32 + t] = np_sumsq256(xs + t, 33);
}

// ---------------- k1: 3-product bf16 MFMA screen (all-A-resident, barrier-free loop) ----------------
// grid 512 x 512 thr (8 waves, launch_bounds(512,2) -> 256-reg budget; 1 block/CU).
// Round 17 lesson: at 1 block/CU, per-cc barriers stall the whole CU (occupancy
// 19.7% = 8 waves). Fix: stage ALL A (64 KB = 8cc x 8KB) in ONE GLD16 burst with
// ONE barrier, then a barrier-free cc loop: ds_read A || global B || MFMA overlap
// freely across the 2 waves/SIMD. T5 setprio(1) wraps each 12-MFMA burst (role
// split now exists: load-issuing vs MFMA waves).
// Also emits distg[n] = min g (est) for the loss (k3 no longer reads x).
// dot_est = xh*eh + xh*el + xl*eh in ONE fp32 acc; margin covers np two-fl
// rounding slop (6.2e-5) + est error (<1e-5). C/D: col=lane&15, row=(lane>>4)*4+j.
__global__ __launch_bounds__(512, 2) void k1_mfma(
        const unsigned short* __restrict__ axP,
        const unsigned short* __restrict__ ebP,
        const float* __restrict__ see_g,
        unsigned long long* __restrict__ key,
        float* __restrict__ distg,
        int* __restrict__ cnt, int* __restrict__ wl) {
    __shared__ char smem[71680];    // A stage 64KB | lk1 4KB | lg2 2KB (disjoint)
    unsigned long long* lk1 = (unsigned long long*)(smem + 65536);
    float*              lg2 = (float*)(smem + 69632);
    const int t = threadIdx.x;
    const int codeg = t >> 6, l = t & 63;
    const int lrow = l >> 4, lcol = l & 15;
    const int rb = blockIdx.x;
    const int n0 = rb * 64;

    // stage ALL A once: 8 GLD16/thread, one vmcnt-drain + barrier total
    {
        const int sub = codeg >> 2;
        const char* aBase = (const char*)axP;
        char* aDst = smem + codeg * 1024;           // wave-uniform
#pragma unroll
        for (int cc = 0; cc < 8; cc++) {
            const char* src = aBase + ((size_t)((rb * 2 + sub) * 8 + cc)) * 4096
                              + (size_t)(codeg & 3) * 1024 + (size_t)l * 16;
            GLD16(src, aDst + cc * 8192);
        }
    }
    __syncthreads();                                // A resident for entire loop

    float4v acc[4][8];
#pragma unroll
    for (int at = 0; at < 4; at++)
#pragma unroll
        for (int ct = 0; ct < 8; ct++) acc[at][ct] = (float4v){0.f, 0.f, 0.f, 0.f};

    for (int cc = 0; cc < 8; cc++) {
        short8v ah[4], al[4];
#pragma unroll
        for (int at = 0; at < 4; at++) {
            const int off = cc * 8192 + (at >> 1) * 4096 + (at & 1) * 2048;
            ah[at] = *(const short8v*)(smem + off + l * 16);
            al[at] = *(const short8v*)(smem + off + 1024 + l * 16);
        }
#pragma unroll
        for (int ct = 0; ct < 8; ct++) {
            const size_t bb = ((((size_t)codeg * 8 + cc) * 8 + ct) * 2) * 512 + (size_t)l * 8;
            const short8v bh = *(const short8v*)(ebP + bb);
            const short8v bl = *(const short8v*)(ebP + bb + 512);
            __builtin_amdgcn_s_setprio(1);
#pragma unroll
            for (int at = 0; at < 4; at++) {
                acc[at][ct] = __builtin_amdgcn_mfma_f32_16x16x32_bf16(ah[at], bh, acc[at][ct], 0, 0, 0);
                acc[at][ct] = __builtin_amdgcn_mfma_f32_16x16x32_bf16(ah[at], bl, acc[at][ct], 0, 0, 0);
                acc[at][ct] = __builtin_amdgcn_mfma_f32_16x16x32_bf16(al[at], bh, acc[at][ct], 0, 0, 0);
            }
            __builtin_amdgcn_s_setprio(0);
        }
    }

    float sv[8];
#pragma unroll
    for (int ct = 0; ct < 8; ct++) sv[ct] = see_g[codeg * 128 + ct * 16 + lcol];

    // per-row top-2 of g = see - 2*dot_est  (sxx row-constant: order-neutral)
#pragma unroll
    for (int at = 0; at < 4; at++) {
#pragma unroll
        for (int j = 0; j < 4; j++) {
            unsigned long long K1 = ~0ull; float G1 = FLT_BIG, G2 = FLT_BIG;
#pragma unroll
            for (int ct = 0; ct < 8; ct++) {
                const float g = fmaf(-2.f, acc[at][ct][j], sv[ct]);
                const int k = codeg * 128 + ct * 16 + lcol;
                const unsigned long long pk =
                    ((unsigned long long)f32_sortable(g) << 32) | (unsigned int)k;
                if (pk < K1) { G2 = G1; K1 = pk; G1 = g; }
                else         { G2 = fminf(G2, g); }
            }
#pragma unroll
            for (int m = 1; m < 16; m <<= 1) {
                const unsigned long long oK = __shfl_xor(K1, m, 64);
                const float oG2 = __shfl_xor(G2, m, 64);
                const float oG1 = f32_unsortable((unsigned int)(oK >> 32));
                if (oK < K1) { G2 = fminf(oG2, G1); K1 = oK; G1 = oG1; }
                else         { G2 = fminf(G2, oG1); }
            }
            const int rloc = at * 16 + lrow * 4 + j;     // row within 64-row block
            if (lcol == 0) { lk1[rloc * 8 + codeg] = K1; lg2[rloc * 8 + codeg] = G2; }
        }
    }
    __syncthreads();
    if (t < 64) {
        unsigned long long K1 = ~0ull; float G1 = FLT_BIG, G2 = FLT_BIG;
        for (int cg = 0; cg < 8; cg++) {
            const unsigned long long oK = lk1[t * 8 + cg];
            const float oG2 = lg2[t * 8 + cg];
            const float oG1 = f32_unsortable((unsigned int)(oK >> 32));
            if (oK < K1) { G2 = fminf(oG2, G1); K1 = oK; G1 = oG1; }
            else         { G2 = fminf(G2, oG1); }
        }
        const int n = n0 + t;
        distg[n] = G1;                   // min g estimate (for loss; err <= margin)
        if (G2 - G1 > MARGIN) { key[n] = K1; }
        else { key[n] = ~0ull; wl[atomicAdd(cnt, 1)] = n; }
    }
}

// ---------------- k2r: np-exact fp32-chain rescan (coalesced via eT) ----------------
__global__ __launch_bounds__(256) void k2r(const float* __restrict__ x,
                                           const float* __restrict__ eT,
                                           const float* __restrict__ see,
                                           const float* __restrict__ sxx,
                                           unsigned long long* __restrict__ key,
                                           const int* __restrict__ cnt,
                                           const int* __restrict__ wl) {
    __shared__ float xs[8][264];
    const int t = threadIdx.x;
    const int total = *cnt;
    for (int base = blockIdx.x * 8; base < total; base += 128 * 8) {
        int nrow[8]; float sx8[8];
#pragma unroll
        for (int r = 0; r < 8; r++) {
            int idx = base + r; if (idx >= total) idx = total - 1;   // benign dup
            const int n = wl[idx];
            nrow[r] = n; sx8[r] = sxx[n];
        }
        __syncthreads();                 // prior batch's xs reads done
#pragma unroll
        for (int r = 0; r < 8; r++) {
            const int n = nrow[r];
            xs[r][t] = x[(size_t)(n >> 10) * 262144 + (size_t)t * 1024 + (n & 1023)];
        }
        __syncthreads();
        float d[8][4];
#pragma unroll
        for (int r = 0; r < 8; r++)
#pragma unroll
            for (int j = 0; j < 4; j++) d[r][j] = 0.f;
#pragma unroll 4
        for (int c = 0; c < 256; c++) {
            float ev[4];
#pragma unroll
            for (int j = 0; j < 4; j++) ev[j] = eT[(size_t)c * 1024 + t + 256 * j];
#pragma unroll
            for (int r = 0; r < 8; r++) {
                const float xv = xs[r][c];
                d[r][0] = fmaf(xv, ev[0], d[r][0]);
                d[r][1] = fmaf(xv, ev[1], d[r][1]);
                d[r][2] = fmaf(xv, ev[2], d[r][2]);
                d[r][3] = fmaf(xv, ev[3], d[r][3]);
            }
        }
#pragma unroll
        for (int r = 0; r < 8; r++) {
            unsigned long long best = ~0ull;
#pragma unroll
            for (int j = 0; j < 4; j++) {
                const float q = fmaf(-2.f, d[r][j], sx8[r]) + see[t + 256 * j];
                const unsigned long long pk =
                    ((unsigned long long)f32_sortable(q) << 32) | (unsigned int)(t + 256 * j);
                best = pk < best ? pk : best;
            }
            atomicMin(&key[nrow[r]], best);
        }
    }
}

// ---------------- k_loss: loss = sum over rows of (sxx[n] + distg[n]) ----------------
// Runs BEFORE k3 (which overwrites the distg region with indices).
__global__ __launch_bounds__(256) void k_loss(const float* __restrict__ sxx,
                                              const float* __restrict__ distg,
                                              double* __restrict__ loss) {
    __shared__ double red[256];
    const int t = threadIdx.x;
    const int base = blockIdx.x * 1024 + t;         // grid 32
    double sd = 0.0;
#pragma unroll
    for (int i = 0; i < 4; i++) {
        const int n = base + i * 256;
        sd += (double)(sxx[n] + distg[n]);
    }
    red[t] = sd;
    __syncthreads();
    for (int s = 128; s > 0; s >>= 1) {
        if (t < s) red[t] += red[t + s];
        __syncthreads();
    }
    if (t == 0) atomicAdd(loss, red[0]);
}

// ---------------- k3: gather quantized + indices (no x read, no loss) ----------------
__global__ __launch_bounds__(256) void k3_out(const float* __restrict__ emb,
                                              const unsigned long long* __restrict__ key,
                                              float* __restrict__ dout) {
    __shared__ float elds[32][257];
    __shared__ int   idxs[32];
    const int t  = threadIdx.x;
    const int bh = blockIdx.x;
    const int b = bh >> 5, h = bh & 31;
    if (t < 32) idxs[t] = (int)(key[(bh << 5) + t] & 0xffffffffull);
    __syncthreads();
    for (int r = 0; r < 32; r++) elds[r][t] = emb[(size_t)idxs[r] * 256 + t];
    __syncthreads();
    const int w = t & 31, cg = t >> 5;
    const size_t base = (size_t)b * 262144 + (size_t)(h * 32 + w);
#pragma unroll 4
    for (int s = 0; s < 32; s++) {
        const int c = (cg << 5) + s;
        dout[base + (size_t)c * 1024] = elds[w][c];
    }
    if (t < 32) dout[IDX_OFF + (bh << 5) + t] = (float)idxs[t];
}

// ---------------- k4: finalize loss ----------------
__global__ void k4_fin(const double* __restrict__ loss, float* __restrict__ dout) {
    dout[LOSS_OFF] = (float)(1.25 * (*loss) / 8388608.0);
}

extern "C" void kernel_launch(void* const* d_in, const int* in_sizes, int n_in,
                              void* d_out, int out_size, void* d_ws, size_t ws_size,
                              hipStream_t stream) {
    const float* x   = (const float*)d_in[0];
    const float* emb = (const float*)d_in[1];
    float* dout = (float*)d_out;
    char* ws = (char*)d_ws;
    float*  see  = (float*)(ws + WS_SEE);
    float*  sxx  = (float*)(ws + WS_SXX);
    unsigned long long* key = (unsigned long long*)(ws + WS_KEY);
    int*    cnt  = (int*)(ws + WS_CNT);
    double* loss = (double*)(ws + WS_LOSS);
    int*    wl   = (int*)(ws + WS_WL);
    unsigned short* ebP = (unsigned short*)(ws + WS_EP);
    float*  eT   = (float*)(ws + WS_EP);      // same region: ebP dead after k1
    // packed A fragments parked in d_out's quantized region (32 MB, k3 overwrites);
    // distg parked in d_out's indices region (128 KB, k3 overwrites after k_loss)
    unsigned short* axP = (unsigned short*)d_out;
    float* distg = dout + IDX_OFF;

    k_prep <<<260,  256, 0, stream>>>(emb, ebP, see, cnt, loss);
    k_xpack<<<1024, 256, 0, stream>>>(x, axP, sxx);
    k1_mfma<<<512,  512, 0, stream>>>(axP, ebP, see, key, distg, cnt, wl);
    k_et   <<<64,   256, 0, stream>>>(emb, eT);          // overwrites ebP region
    k2r    <<<128,  256, 0, stream>>>(x, eT, see, sxx, key, cnt, wl);
    k_loss <<<32,   256, 0, stream>>>(sxx, distg, loss); // before k3 clobbers distg
    k3_out <<<1024, 256, 0, stream>>>(emb, key, dout);
    k4_fin <<<1,      1, 0, stream>>>(loss, dout);
}

// Round 19
// 188.946 us; speedup vs baseline: 1.9256x; 1.0583x over previous
//
#include <hip/hip_runtime.h>

#define LOSS_OFF 8388608
#define IDX_OFF  8388609

// ws layout (bytes)  (total ~1.58 MB)
#define WS_SEE   0          // float[1024]
#define WS_SXX   4096       // float[32768]   -> 135168
#define WS_KEY   135168     // u64[32768]     -> 397312
#define WS_CNT   397312     // int
#define WS_LOSS  397320     // double
#define WS_WL    397328     // int[32768]     -> 528400
#define WS_EP    528448     // packed E frags (1 MB) during k1; REUSED as eT[c][k] after k1

#define FLT_BIG  3.402823466e+38f
#define MARGIN   1.0e-4f

typedef __attribute__((ext_vector_type(8))) short  short8v;
typedef __attribute__((ext_vector_type(4))) float  float4v;

// async global->LDS, 16B per lane; LDS dest = wave-uniform base (+ lane*16 by HW)
#define GLD16(gp, lp) __builtin_amdgcn_global_load_lds( \
    (const __attribute__((address_space(1))) unsigned int*)(gp), \
    (__attribute__((address_space(3))) unsigned int*)(lp), 16, 0, 0)

// numpy pairwise_sum of 256 squared elements, bit-exact (round-2 notes).
__device__ __forceinline__ float np_sumsq256(const float* __restrict__ p, int stride) {
    float s[2];
#pragma unroll
    for (int half = 0; half < 2; half++) {
        const float* a = p + half * 128 * stride;
        float r[8];
#pragma unroll
        for (int l = 0; l < 8; l++) {
            float v = a[l * stride];
            float sq = v * v;
            asm volatile("" : "+v"(sq));   // forbid fma contraction
            r[l] = sq;
        }
#pragma unroll
        for (int i = 8; i < 128; i += 8) {
#pragma unroll
            for (int l = 0; l < 8; l++) {
                float v = a[(i + l) * stride];
                float sq = v * v;
                asm volatile("" : "+v"(sq));
                r[l] = r[l] + sq;
            }
        }
        s[half] = ((r[0] + r[1]) + (r[2] + r[3])) + ((r[4] + r[5]) + (r[6] + r[7]));
    }
    return s[0] + s[1];
}

__device__ __forceinline__ unsigned int f32_sortable(float m) {
    unsigned int u = __float_as_uint(m);
    return u ^ (((unsigned int)((int)u >> 31)) | 0x80000000u);
}
__device__ __forceinline__ float f32_unsortable(unsigned int s) {   // inverse
    const unsigned int u = (s >> 31) ? (s ^ 0x80000000u) : ~s;
    return __uint_as_float(u);
}

__device__ __forceinline__ unsigned short f2bf(float f) {      // RNE float->bf16
    unsigned int u = __float_as_uint(f);
    return (unsigned short)((u + 0x7fffu + ((u >> 16) & 1u)) >> 16);
}
__device__ __forceinline__ float bf2f(unsigned short h) {
    return __uint_as_float(((unsigned int)h) << 16);
}

// ---------------- k_prep: epack (blocks 0..255) + see/init (blocks 256..259) ----------------
__global__ __launch_bounds__(256) void k_prep(const float* __restrict__ emb,
                                              unsigned short* __restrict__ ebP,
                                              float* __restrict__ see,
                                              int* __restrict__ cnt,
                                              double* __restrict__ loss) {
    const int t = threadIdx.x, bb = blockIdx.x;
    if (bb < 256) {
        const int idx = bb * 256 + t;
        const int l  = idx & 63;
        const int ph = (idx >> 6) & 1;
        const int ct = (idx >> 7) & 7;
        const int cc = (idx >> 10) & 7;
        const int cg = (idx >> 13) & 7;
        const int row = cg * 128 + ct * 16 + (l & 15);
        const int col = cc * 32 + (l >> 4) * 8;
        const float* src = emb + (size_t)row * 256 + col;
        uint4 out;
        unsigned short* op = (unsigned short*)&out;
#pragma unroll
        for (int i = 0; i < 8; i++) {
            const float v = src[i];
            const unsigned short h = f2bf(v);
            op[i] = ph ? f2bf(v - bf2f(h)) : h;      // v-h exact (Sterbenz)
        }
        *(uint4*)(ebP + (size_t)idx * 8) = out;
    } else {
        const int k = (bb - 256) * 256 + t;
        see[k] = np_sumsq256(emb + (size_t)k * 256, 1);
        if (k == 0) { *cnt = 0; *loss = 0.0; }
    }
}

// ---------------- k_et: transpose codebook -> eT[c][k] (runs AFTER k1) ----------------
__global__ __launch_bounds__(256) void k_et(const float* __restrict__ emb,
                                            float* __restrict__ eT) {
    __shared__ float T[256][17];
    const int t  = threadIdx.x;
    const int k0 = blockIdx.x << 4;                 // grid 64
    const int kr = t >> 4, cs = (t & 15) << 4;
#pragma unroll
    for (int j = 0; j < 4; j++) {
        const float4 v = *(const float4*)(emb + (size_t)(k0 + kr) * 256 + cs + j * 4);
        T[cs + j * 4 + 0][kr] = v.x;
        T[cs + j * 4 + 1][kr] = v.y;
        T[cs + j * 4 + 2][kr] = v.z;
        T[cs + j * 4 + 3][kr] = v.w;
    }
    __syncthreads();
    float* dst = eT + (size_t)t * 1024 + k0;
#pragma unroll
    for (int j = 0; j < 4; j++) {
        float4 v;
        v.x = T[t][j * 4 + 0]; v.y = T[t][j * 4 + 1];
        v.z = T[t][j * 4 + 2]; v.w = T[t][j * 4 + 3];
        *(float4*)(dst + j * 4) = v;
    }
}

// ---------------- k1: fused stage+split+sxx+MFMA screen+loss partial ----------------
// grid 512 x 512 thr (8 waves, launch_bounds(512,2); LDS 128 KB -> 1 block/CU).
// Phase A: GLD16 x rows (64 x 256c, 64KB f32, [c][row] linear). Phase C: cooperative
// bf16 hi/lo split into packed fragments (bit-identical to old k_xpack). Phase B:
// sxx via np_sumsq256 (verbatim, stride 64) by wave 0. Main loop = round-18's
// (barrier-free, setprio). Tail: top-2 fold + margin/worklist + per-block loss
// partial sum(sxx + G1) (est min; err <= margin -> ~1e-8 relative on loss).
// Replaces k_xpack + k_loss and kills the axP/distg d_out aliasing (8->6 launches,
// -67 MB intermediate traffic).
__global__ __launch_bounds__(512, 2) void k1_mfma(
        const float* __restrict__ x,
        const unsigned short* __restrict__ ebP,
        const float* __restrict__ see_g,
        float* __restrict__ sxx_g,
        unsigned long long* __restrict__ key,
        double* __restrict__ loss,
        int* __restrict__ cnt, int* __restrict__ wl) {
    __shared__ char smem[131072];
    // [0,64K): x f32 stage [c(256)][row(64)] -- dead after phases B/C; aliased by reduce
    // [64K,128K): bf16 fragments [cc(8)][at(4)][ph(2)][l(64)][16B]
    unsigned long long* lk1 = (unsigned long long*)smem;          // [64][8] 4 KB
    float*              lg2 = (float*)(smem + 4096);              // [64][8] 2 KB
    float* xstage = (float*)smem;
    char*  frag   = smem + 65536;

    const int t = threadIdx.x;
    const int w = t >> 6, l = t & 63;
    const int codeg = w;
    const int lrow = l >> 4, lcol = l & 15;
    const int rb = blockIdx.x;
    const int n0 = rb * 64;
    const int b  = rb >> 4;
    const int hw0 = (rb & 15) << 6;

    // Phase A: stage x -> LDS [c][row] f32 (each wave: 4 contiguous 256B c-segments/round)
    {
        const char* xbyte = (const char*)x + ((size_t)b * 262144 + hw0) * 4;
#pragma unroll
        for (int i = 0; i < 8; i++) {
            const int cbase = i * 32 + w * 4;
            const char* src = xbyte + (size_t)(cbase + (l >> 4)) * 4096 + (size_t)(l & 15) * 16;
            GLD16(src, smem + cbase * 256);
        }
    }
    __syncthreads();

    // Phase C: cooperative bf16 hi/lo split -> packed fragments (4 chunk-pairs/thread)
#pragma unroll
    for (int ii = 0; ii < 4; ii++) {
        const int pi  = ii * 512 + t;          // 0..2047 = [cc(8)][at(4)][l(64)]
        const int pcc = pi >> 8;
        const int pat = (pi >> 6) & 3;
        const int pl  = pi & 63;
        const int prow = pat * 16 + (pl & 15);
        const int pc0  = pcc * 32 + (pl >> 4) * 8;
        uint4 hp, lp;
        unsigned short* hpp = (unsigned short*)&hp;
        unsigned short* lpp = (unsigned short*)&lp;
#pragma unroll
        for (int i = 0; i < 8; i++) {
            const float v = xstage[(pc0 + i) * 64 + prow];
            const unsigned short h = f2bf(v);
            hpp[i] = h;
            lpp[i] = f2bf(v - bf2f(h));        // exact (Sterbenz)
        }
        char* dst = frag + pcc * 8192 + pat * 2048 + pl * 16;
        *(uint4*)dst = hp;
        *(uint4*)(dst + 1024) = lp;
    }
    // Phase B: per-row ||x||^2, np-exact (wave 0; one row per lane)
    float sx_reg = 0.f;
    if (t < 64) {
        sx_reg = np_sumsq256(xstage + t, 64);
        sxx_g[n0 + t] = sx_reg;
    }
    __syncthreads();                            // frags+sxx ready; xstage dead

    float4v acc[4][8];
#pragma unroll
    for (int at = 0; at < 4; at++)
#pragma unroll
        for (int ct = 0; ct < 8; ct++) acc[at][ct] = (float4v){0.f, 0.f, 0.f, 0.f};

    for (int cc = 0; cc < 8; cc++) {
        short8v ah[4], al[4];
#pragma unroll
        for (int at = 0; at < 4; at++) {
            const int off = cc * 8192 + at * 2048 + l * 16;
            ah[at] = *(const short8v*)(frag + off);
            al[at] = *(const short8v*)(frag + off + 1024);
        }
#pragma unroll
        for (int ct = 0; ct < 8; ct++) {
            const size_t bb = ((((size_t)codeg * 8 + cc) * 8 + ct) * 2) * 512 + (size_t)l * 8;
            const short8v bh = *(const short8v*)(ebP + bb);
            const short8v bl = *(const short8v*)(ebP + bb + 512);
            __builtin_amdgcn_s_setprio(1);
#pragma unroll
            for (int at = 0; at < 4; at++) {
                acc[at][ct] = __builtin_amdgcn_mfma_f32_16x16x32_bf16(ah[at], bh, acc[at][ct], 0, 0, 0);
                acc[at][ct] = __builtin_amdgcn_mfma_f32_16x16x32_bf16(ah[at], bl, acc[at][ct], 0, 0, 0);
                acc[at][ct] = __builtin_amdgcn_mfma_f32_16x16x32_bf16(al[at], bh, acc[at][ct], 0, 0, 0);
            }
            __builtin_amdgcn_s_setprio(0);
        }
    }

    float sv[8];
#pragma unroll
    for (int ct = 0; ct < 8; ct++) sv[ct] = see_g[codeg * 128 + ct * 16 + lcol];

    // per-row top-2 of g = see - 2*dot_est  (sxx row-constant: order-neutral)
#pragma unroll
    for (int at = 0; at < 4; at++) {
#pragma unroll
        for (int j = 0; j < 4; j++) {
            unsigned long long K1 = ~0ull; float G1 = FLT_BIG, G2 = FLT_BIG;
#pragma unroll
            for (int ct = 0; ct < 8; ct++) {
                const float g = fmaf(-2.f, acc[at][ct][j], sv[ct]);
                const int k = codeg * 128 + ct * 16 + lcol;
                const unsigned long long pk =
                    ((unsigned long long)f32_sortable(g) << 32) | (unsigned int)k;
                if (pk < K1) { G2 = G1; K1 = pk; G1 = g; }
                else         { G2 = fminf(G2, g); }
            }
#pragma unroll
            for (int m = 1; m < 16; m <<= 1) {
                const unsigned long long oK = __shfl_xor(K1, m, 64);
                const float oG2 = __shfl_xor(G2, m, 64);
                const float oG1 = f32_unsortable((unsigned int)(oK >> 32));
                if (oK < K1) { G2 = fminf(oG2, G1); K1 = oK; G1 = oG1; }
                else         { G2 = fminf(G2, oG1); }
            }
            const int rloc = at * 16 + lrow * 4 + j;
            if (lcol == 0) { lk1[rloc * 8 + codeg] = K1; lg2[rloc * 8 + codeg] = G2; }
        }
    }
    __syncthreads();
    if (t < 64) {
        unsigned long long K1 = ~0ull; float G1 = FLT_BIG, G2 = FLT_BIG;
        for (int cg = 0; cg < 8; cg++) {
            const unsigned long long oK = lk1[t * 8 + cg];
            const float oG2 = lg2[t * 8 + cg];
            const float oG1 = f32_unsortable((unsigned int)(oK >> 32));
            if (oK < K1) { G2 = fminf(oG2, G1); K1 = oK; G1 = oG1; }
            else         { G2 = fminf(G2, oG1); }
        }
        const int n = n0 + t;
        if (G2 - G1 > MARGIN) { key[n] = K1; }
        else { key[n] = ~0ull; wl[atomicAdd(cnt, 1)] = n; }
        // loss partial: sum over this block's 64 rows of (sxx + min-dist est)
        float part = sx_reg + G1;
#pragma unroll
        for (int m = 1; m < 64; m <<= 1) part += __shfl_xor(part, m, 64);
        if (t == 0) atomicAdd(loss, (double)part);
    }
}

// ---------------- k2r: np-exact fp32-chain rescan (coalesced via eT) ----------------
__global__ __launch_bounds__(256) void k2r(const float* __restrict__ x,
                                           const float* __restrict__ eT,
                                           const float* __restrict__ see,
                                           const float* __restrict__ sxx,
                                           unsigned long long* __restrict__ key,
                                           const int* __restrict__ cnt,
                                           const int* __restrict__ wl) {
    __shared__ float xs[8][264];
    const int t = threadIdx.x;
    const int total = *cnt;
    for (int base = blockIdx.x * 8; base < total; base += 128 * 8) {
        int nrow[8]; float sx8[8];
#pragma unroll
        for (int r = 0; r < 8; r++) {
            int idx = base + r; if (idx >= total) idx = total - 1;   // benign dup
            const int n = wl[idx];
            nrow[r] = n; sx8[r] = sxx[n];
        }
        __syncthreads();                 // prior batch's xs reads done
#pragma unroll
        for (int r = 0; r < 8; r++) {
            const int n = nrow[r];
            xs[r][t] = x[(size_t)(n >> 10) * 262144 + (size_t)t * 1024 + (n & 1023)];
        }
        __syncthreads();
        float d[8][4];
#pragma unroll
        for (int r = 0; r < 8; r++)
#pragma unroll
            for (int j = 0; j < 4; j++) d[r][j] = 0.f;
#pragma unroll 4
        for (int c = 0; c < 256; c++) {
            float ev[4];
#pragma unroll
            for (int j = 0; j < 4; j++) ev[j] = eT[(size_t)c * 1024 + t + 256 * j];
#pragma unroll
            for (int r = 0; r < 8; r++) {
                const float xv = xs[r][c];
                d[r][0] = fmaf(xv, ev[0], d[r][0]);
                d[r][1] = fmaf(xv, ev[1], d[r][1]);
                d[r][2] = fmaf(xv, ev[2], d[r][2]);
                d[r][3] = fmaf(xv, ev[3], d[r][3]);
            }
        }
#pragma unroll
        for (int r = 0; r < 8; r++) {
            unsigned long long best = ~0ull;
#pragma unroll
            for (int j = 0; j < 4; j++) {
                const float q = fmaf(-2.f, d[r][j], sx8[r]) + see[t + 256 * j];
                const unsigned long long pk =
                    ((unsigned long long)f32_sortable(q) << 32) | (unsigned int)(t + 256 * j);
                best = pk < best ? pk : best;
            }
            atomicMin(&key[nrow[r]], best);
        }
    }
}

// ---------------- k3: gather quantized + indices ----------------
__global__ __launch_bounds__(256) void k3_out(const float* __restrict__ emb,
                                              const unsigned long long* __restrict__ key,
                                              float* __restrict__ dout) {
    __shared__ float elds[32][257];
    __shared__ int   idxs[32];
    const int t  = threadIdx.x;
    const int bh = blockIdx.x;
    const int b = bh >> 5, h = bh & 31;
    if (t < 32) idxs[t] = (int)(key[(bh << 5) + t] & 0xffffffffull);
    __syncthreads();
    for (int r = 0; r < 32; r++) elds[r][t] = emb[(size_t)idxs[r] * 256 + t];
    __syncthreads();
    const int w = t & 31, cg = t >> 5;
    const size_t base = (size_t)b * 262144 + (size_t)(h * 32 + w);
#pragma unroll 4
    for (int s = 0; s < 32; s++) {
        const int c = (cg << 5) + s;
        dout[base + (size_t)c * 1024] = elds[w][c];
    }
    if (t < 32) dout[IDX_OFF + (bh << 5) + t] = (float)idxs[t];
}

// ---------------- k4: finalize loss ----------------
__global__ void k4_fin(const double* __restrict__ loss, float* __restrict__ dout) {
    dout[LOSS_OFF] = (float)(1.25 * (*loss) / 8388608.0);
}

extern "C" void kernel_launch(void* const* d_in, const int* in_sizes, int n_in,
                              void* d_out, int out_size, void* d_ws, size_t ws_size,
                              hipStream_t stream) {
    const float* x   = (const float*)d_in[0];
    const float* emb = (const float*)d_in[1];
    float* dout = (float*)d_out;
    char* ws = (char*)d_ws;
    float*  see  = (float*)(ws + WS_SEE);
    float*  sxx  = (float*)(ws + WS_SXX);
    unsigned long long* key = (unsigned long long*)(ws + WS_KEY);
    int*    cnt  = (int*)(ws + WS_CNT);
    double* loss = (double*)(ws + WS_LOSS);
    int*    wl   = (int*)(ws + WS_WL);
    unsigned short* ebP = (unsigned short*)(ws + WS_EP);
    float*  eT   = (float*)(ws + WS_EP);      // same region: ebP dead after k1

    k_prep <<<260,  256, 0, stream>>>(emb, ebP, see, cnt, loss);
    k1_mfma<<<512,  512, 0, stream>>>(x, ebP, see, sxx, key, loss, cnt, wl);
    k_et   <<<64,   256, 0, stream>>>(emb, eT);          // overwrites ebP region
    k2r    <<<128,  256, 0, stream>>>(x, eT, see, sxx, key, cnt, wl);
    k3_out <<<1024, 256, 0, stream>>>(emb, key, dout);
    k4_fin <<<1,      1, 0, stream>>>(loss, dout);
}